// Round 12
// baseline (801.817 us; speedup 1.0000x reference)
//
#include <hip/hip_runtime.h>
#include <hip/hip_bf16.h>
#include <math.h>

// Problem constants: B=4, T=512, I=128, H=128 (4H=512)
#define Bq 4
#define Tq 512
#define Hq 128

typedef _Float16 f16x4 __attribute__((ext_vector_type(4)));
typedef _Float16 f16x8 __attribute__((ext_vector_type(8)));
typedef float f32x4 __attribute__((ext_vector_type(4)));

// fast reciprocal (v_rcp_f32, ~1ulp) -- avoids the IEEE div sequence
__device__ __forceinline__ float rcp_fast(float x) { return __builtin_amdgcn_rcpf(x); }
__device__ __forceinline__ float sigmoid_fast(float x) {
    return rcp_fast(1.0f + __expf(-x));     // exp->inf => rcp->0: correct tail
}
__device__ __forceinline__ float tanh_fast(float x) {
    float e = __expf(2.0f * x);             // e->inf => rcp->0 => tanh->1
    return 1.0f - 2.0f * rcp_fast(e + 1.0f);
}

// ---------------------------------------------------------------------------
// Shared GEMM-nt body: C[m,n] = sum_k A[m,k]*W[n,k] (+bias) (+=C), K=128.
// ---------------------------------------------------------------------------
__device__ __forceinline__ void gemm_nt_body(float (*As)[68], float (*Ws)[68],
                                             const float* __restrict__ A, int lda,
                                             const float* __restrict__ W, int ldw,
                                             const float* __restrict__ bias,
                                             float* __restrict__ C, int acc_flag,
                                             int m0, int n0, int tid) {
    int tx = tid & 15, ty = tid >> 4;
    float acc[4][4] = {};
    for (int kc = 0; kc < 2; kc++) {
        __syncthreads();
#pragma unroll
        for (int i = 0; i < 4; i++) {
            int idx = tid + 256 * i;
            int r = idx >> 4, c4 = idx & 15;
            *(float4*)(&As[r][c4 * 4]) = *(const float4*)(A + (size_t)(m0 + r) * lda + kc * 64 + c4 * 4);
            *(float4*)(&Ws[r][c4 * 4]) = *(const float4*)(W + (size_t)(n0 + r) * ldw + kc * 64 + c4 * 4);
        }
        __syncthreads();
#pragma unroll
        for (int k4 = 0; k4 < 16; k4++) {
            float4 a[4], wv[4];
#pragma unroll
            for (int i = 0; i < 4; i++) a[i] = *(const float4*)(&As[ty * 4 + i][k4 * 4]);
#pragma unroll
            for (int j = 0; j < 4; j++) wv[j] = *(const float4*)(&Ws[tx * 4 + j][k4 * 4]);
#pragma unroll
            for (int i = 0; i < 4; i++)
#pragma unroll
                for (int j = 0; j < 4; j++)
                    acc[i][j] += a[i].x * wv[j].x + a[i].y * wv[j].y + a[i].z * wv[j].z + a[i].w * wv[j].w;
        }
    }
#pragma unroll
    for (int i = 0; i < 4; i++) {
        int m = m0 + ty * 4 + i;
        int n = n0 + tx * 4;
        float4 v = make_float4(acc[i][0], acc[i][1], acc[i][2], acc[i][3]);
        if (bias) { v.x += bias[n]; v.y += bias[n + 1]; v.z += bias[n + 2]; v.w += bias[n + 3]; }
        if (acc_flag) {
            float4 o = *(const float4*)(C + (size_t)m * 512 + n);
            v.x += o.x; v.y += o.y; v.z += o.z; v.w += o.w;
        }
        *(float4*)(C + (size_t)m * 512 + n) = v;
    }
}

// ---------------------------------------------------------------------------
// prep: both input-projection GEMMs + both f16 weight converts (1 launch).
// ---------------------------------------------------------------------------
__global__ __launch_bounds__(256) void prep(const float* __restrict__ x,
                                            const float* __restrict__ Wih_s,
                                            const float* __restrict__ b_s,
                                            const float* __restrict__ Wih_t,
                                            const float* __restrict__ b_t,
                                            const float* __restrict__ Whh_s,
                                            const float* __restrict__ Whh_t,
                                            float* __restrict__ xg_s,
                                            float* __restrict__ xg_t,
                                            _Float16* __restrict__ W16_s,
                                            _Float16* __restrict__ W16_t) {
    __shared__ __align__(16) float As[64][68];
    __shared__ __align__(16) float Ws[64][68];
    int bid = blockIdx.x;
    int tid = threadIdx.x;
    if (bid < 512) {
        int which = bid >> 8;
        int b2 = bid & 255;
        int m0 = (b2 & 31) * 64, n0 = (b2 >> 5) * 64;
        gemm_nt_body(As, Ws, x, 128,
                     which ? Wih_t : Wih_s, which ? 256 : 128,
                     which ? b_t : b_s,
                     which ? xg_t : xg_s, 0, m0, n0, tid);
    } else {
        int cb = bid - 512;                      // 0..127
        const float* in = (cb < 64) ? Whh_s : Whh_t;
        _Float16* out = (cb < 64) ? W16_s : W16_t;
        int i = ((cb & 63) * 256 + tid) * 4;
        float4 v = *(const float4*)(in + i);
        f16x4 o;
        o[0] = (_Float16)v.x; o[1] = (_Float16)v.y;
        o[2] = (_Float16)v.z; o[3] = (_Float16)v.w;
        *(f16x4*)(out + i) = o;
    }
}

// ---------------------------------------------------------------------------
// gemm_nt standalone (R-projection accumulate). grid (32,8), block 256.
// ---------------------------------------------------------------------------
__global__ __launch_bounds__(256) void gemm_nt(const float* __restrict__ A, int lda,
                                               const float* __restrict__ W, int ldw,
                                               const float* __restrict__ bias,
                                               float* __restrict__ C, int acc_flag) {
    __shared__ __align__(16) float As[64][68];
    __shared__ __align__(16) float Ws[64][68];
    gemm_nt_body(As, Ws, A, lda, W, ldw, bias, C, acc_flag,
                 blockIdx.x * 64, blockIdx.y * 64, threadIdx.x);
}

// ---------------------------------------------------------------------------
// mid: both attention-precursor GEMMs in one launch. flat grid 128.
// ---------------------------------------------------------------------------
__global__ __launch_bounds__(256) void mid(const float* __restrict__ x,
                                           const float* __restrict__ Hsh,
                                           const float* __restrict__ Wht,
                                           const float* __restrict__ Wx,
                                           const float* __restrict__ Whs,
                                           const float* __restrict__ bs,
                                           float* __restrict__ hp_t,
                                           float* __restrict__ c_s) {
    __shared__ __align__(16) float As[64][68];
    __shared__ __align__(16) float Bs[64][68];
    int bid = blockIdx.x;
    int cfg = bid >> 6;          // 0: hp_t, 1: c_s
    int b2 = bid & 63;
    int m0 = (b2 & 31) * 64, n0 = (b2 >> 5) * 64;
    const float* A1 = cfg ? x : Hsh;
    const float* B1 = cfg ? Wx : Wht;
    const float* A2 = cfg ? Hsh : nullptr;
    const float* B2 = cfg ? Whs : nullptr;
    const float* bias = cfg ? bs : nullptr;
    float* C = cfg ? c_s : hp_t;

    int tid = threadIdx.x;
    int tx = tid & 15, ty = tid >> 4;
    float acc[4][4] = {};
    for (int src = 0; src < 2; src++) {
        const float* A = src ? A2 : A1;
        const float* Bm = src ? B2 : B1;
        if (!A) break;
        for (int kc = 0; kc < 2; kc++) {
            __syncthreads();
#pragma unroll
            for (int i = 0; i < 4; i++) {
                int idx = tid + 256 * i;
                int r = idx >> 4, c4 = idx & 15;
                *(float4*)(&As[r][c4 * 4]) = *(const float4*)(A + (size_t)(m0 + r) * 128 + kc * 64 + c4 * 4);
                *(float4*)(&Bs[r][c4 * 4]) = *(const float4*)(Bm + (size_t)(kc * 64 + r) * 128 + n0 + c4 * 4);
            }
            __syncthreads();
#pragma unroll
            for (int k4 = 0; k4 < 16; k4++) {
                float4 a[4];
#pragma unroll
                for (int i = 0; i < 4; i++) a[i] = *(const float4*)(&As[ty * 4 + i][k4 * 4]);
#pragma unroll
                for (int kk = 0; kk < 4; kk++) {
                    float4 bv = *(const float4*)(&Bs[k4 * 4 + kk][tx * 4]);
#pragma unroll
                    for (int i = 0; i < 4; i++) {
                        float av = (kk == 0) ? a[i].x : (kk == 1) ? a[i].y : (kk == 2) ? a[i].z : a[i].w;
                        acc[i][0] += av * bv.x;
                        acc[i][1] += av * bv.y;
                        acc[i][2] += av * bv.z;
                        acc[i][3] += av * bv.w;
                    }
                }
            }
        }
    }
#pragma unroll
    for (int i = 0; i < 4; i++) {
        int m = m0 + ty * 4 + i;
        int n = n0 + tx * 4;
        float4 v = make_float4(acc[i][0], acc[i][1], acc[i][2], acc[i][3]);
        if (bias) { v.x += bias[n]; v.y += bias[n + 1]; v.z += bias[n + 2]; v.w += bias[n + 3]; }
        *(float4*)(C + (size_t)m * 128 + n) = v;
    }
}

// ---------------------------------------------------------------------------
// MFMA LSTM, all 4 batches in ONE block (unchanged from R11).
// ---------------------------------------------------------------------------
#define MF0(ACC, A, B) \
    asm("v_mfma_f32_16x16x32_f16 %0, %1, %2, %3" : "=&v"(ACC) : "v"(A), "a"(B), "v"(zro));
#define MF(ACC, A, B) \
    asm("v_mfma_f32_16x16x32_f16 %0, %1, %2, %0" : "+v"(ACC) : "v"(A), "a"(B));

#define LSTM_STEP(X0, X1, X2, X3, R0, R1, R2, R3, WPTR, PXG)                       \
    {                                                                              \
        f16x8 a0 = *(R0); f16x8 a1 = *(R1);                                        \
        f16x8 a2 = *(R2); f16x8 a3 = *(R3);                                        \
        float o0 = X0, o1 = X1, o2 = X2, o3 = X3;                                  \
        X0 = (PXG)[0]; X1 = (PXG)[128]; X2 = (PXG)[256]; X3 = (PXG)[384];          \
        (PXG) += 1024;                                                             \
        f32x4 ac0a, ac1a, ac2a, ac3a, ac0b, ac1b, ac2b, ac3b;                      \
        MF0(ac0a, a0, b00) MF0(ac1a, a0, b10) MF0(ac2a, a0, b20) MF0(ac3a, a0, b30)\
        MF0(ac0b, a2, b02) MF0(ac1b, a2, b12) MF0(ac2b, a2, b22) MF0(ac3b, a2, b32)\
        MF(ac0a, a1, b01) MF(ac1a, a1, b11) MF(ac2a, a1, b21) MF(ac3a, a1, b31)    \
        MF(ac0b, a3, b03) MF(ac1b, a3, b13) MF(ac2b, a3, b23) MF(ac3b, a3, b33)    \
        asm volatile("s_nop 7\n\ts_nop 7"                                          \
                     : "+v"(ac0a), "+v"(ac1a), "+v"(ac2a), "+v"(ac3a),             \
                       "+v"(ac0b), "+v"(ac1b), "+v"(ac2b), "+v"(ac3b));            \
        float gi = ac0a[0] + ac0b[0] + o0;                                         \
        float gf = ac1a[0] + ac1b[0] + o1;                                         \
        float gg = ac2a[0] + ac2b[0] + o2;                                         \
        float go = ac3a[0] + ac3b[0] + o3;                                         \
        float si = sigmoid_fast(gi), sf = sigmoid_fast(gf), so = sigmoid_fast(go); \
        float tg = tanh_fast(gg);                                                  \
        c = sf * c + si * tg;                                                      \
        float h = so * tanh_fast(c);                                               \
        *(WPTR) = (_Float16)h;                                                     \
        *pH = h; pH += Hq;                                                         \
        __builtin_amdgcn_sched_barrier(0);                                         \
        asm volatile("s_waitcnt lgkmcnt(0)");                                      \
        __builtin_amdgcn_s_barrier();                                              \
        __builtin_amdgcn_sched_barrier(0);                                         \
    }

__global__ __launch_bounds__(512)
__attribute__((amdgpu_waves_per_eu(2, 2)))
void lstm_b4(const float* __restrict__ xg,      // [B,T,512]
             const _Float16* __restrict__ W16,  // [512,128] f16
             float* __restrict__ Hout) {        // [B,T,128]
    int tid = threadIdx.x;
    int w = tid >> 6, lane = tid & 63;
    int r = lane & 15, kg = lane >> 4;   // kg = k-group AND batch id
    int ch = 16 * w + r;

    __shared__ _Float16 hbuf[2][16][128];
    _Float16* hbase = &hbuf[0][0][0];
    for (int i = tid; i < 4096; i += 512) hbase[i] = (_Float16)0.f;

    const _Float16* wb = W16 + (size_t)ch * 128 + kg * 8;
#define LWB(g, kb) *(const f16x8*)(wb + (size_t)(g) * 16384 + (kb) * 32)
    f16x8 b00 = LWB(0, 0), b01 = LWB(0, 1), b02 = LWB(0, 2), b03 = LWB(0, 3);
    f16x8 b10 = LWB(1, 0), b11 = LWB(1, 1), b12 = LWB(1, 2), b13 = LWB(1, 3);
    f16x8 b20 = LWB(2, 0), b21 = LWB(2, 1), b22 = LWB(2, 2), b23 = LWB(2, 3);
    f16x8 b30 = LWB(3, 0), b31 = LWB(3, 1), b32 = LWB(3, 2), b33 = LWB(3, 3);
#undef LWB
    f32x4 zro = {0.f, 0.f, 0.f, 0.f};
    asm volatile(""
                 : "+a"(b00), "+a"(b01), "+a"(b02), "+a"(b03),
                   "+a"(b10), "+a"(b11), "+a"(b12), "+a"(b13),
                   "+a"(b20), "+a"(b21), "+a"(b22), "+a"(b23),
                   "+a"(b30), "+a"(b31), "+a"(b32), "+a"(b33),
                   "+v"(zro));

    int aoff0 = r * 128 + (((0 * 4 + kg) ^ r) << 3);
    int aoff1 = r * 128 + (((1 * 4 + kg) ^ r) << 3);
    int aoff2 = r * 128 + (((2 * 4 + kg) ^ r) << 3);
    int aoff3 = r * 128 + (((3 * 4 + kg) ^ r) << 3);
    int woff = (4 * kg) * 128 + (((ch >> 3) ^ (4 * kg)) << 3) + (ch & 7);

    const f16x8* rA0 = (const f16x8*)(hbase + aoff0);
    const f16x8* rA1 = (const f16x8*)(hbase + aoff1);
    const f16x8* rA2 = (const f16x8*)(hbase + aoff2);
    const f16x8* rA3 = (const f16x8*)(hbase + aoff3);
    const f16x8* rB0 = (const f16x8*)(hbase + 2048 + aoff0);
    const f16x8* rB1 = (const f16x8*)(hbase + 2048 + aoff1);
    const f16x8* rB2 = (const f16x8*)(hbase + 2048 + aoff2);
    const f16x8* rB3 = (const f16x8*)(hbase + 2048 + aoff3);
    _Float16* wA = hbase + 2048 + woff;
    _Float16* wB = hbase + woff;

    size_t kgTq = (size_t)kg * Tq;
    const float* xgb = xg;
    const float* p0 = xgb + (kgTq + 0) * 512 + ch;
    const float* p1 = xgb + (kgTq + 1) * 512 + ch;
    float xa0 = p0[0], xa1 = p0[128], xa2 = p0[256], xa3 = p0[384];
    float xb0 = p1[0], xb1 = p1[128], xb2 = p1[256], xb3 = p1[384];
    const float* pA = xgb + (kgTq + 2) * 512 + ch;
    const float* pB = xgb + (kgTq + 3) * 512 + ch;
    float* pH = Hout + kgTq * Hq + ch;

    float c = 0.f;
    __syncthreads();

    for (int t = 0; t < Tq; t += 2) {
        LSTM_STEP(xa0, xa1, xa2, xa3, rA0, rA1, rA2, rA3, wA, pA)
        LSTM_STEP(xb0, xb1, xb2, xb3, rB0, rB1, rB2, rB3, wB, pB)
    }
}

// ---------------------------------------------------------------------------
// Attention v3 (t-tiled): ONE block handles 8 t-values -> c_s and Hsh are
// read ONCE per 8 t (L2 traffic /8 vs R11: 1GB -> 128MB). grid (64,4),
// block 256. Thread (h8=tid&31 -> 4 h-channels, tq=tid>>5 -> one t).
// Scores: per s, one coalesced float4 c_s read (lanes 0-31 contiguous 512B;
// tq half-waves hit same lines), 4 tanh/lane, shfl_xor h-reduce (5 stages),
// exp; denominator accumulated fully in-register (all lanes of a tq-group
// identical). sc[8][512] LDS (16KB). PV: float4 Hsh loads + float4 sc LDS
// reads, register acc, one barrier total. No max-subtraction (|score| <=
// ||u||_1 ~ 10, f32-safe; ratio exact -- R10/R11 passed with this).
// ---------------------------------------------------------------------------
__global__ __launch_bounds__(256) void attn_kernel(const float* __restrict__ hp_t,
                                                   const float* __restrict__ c_s,
                                                   const float* __restrict__ u,
                                                   const float* __restrict__ Hsh,
                                                   float* __restrict__ R) {
    int t0 = blockIdx.x * 8;
    int b = blockIdx.y;
    int tid = threadIdx.x;
    int h8 = tid & 31;          // handles h[h8*4 .. h8*4+4)
    int tq = tid >> 5;          // 0..7 -> t = t0 + tq

    __shared__ __align__(16) float a_lds[8][128];
    __shared__ __align__(16) float sc[8][512];

    // load 8 hp_t rows (1024 floats, one float4 per thread)
    {
        int idx = tid * 4;
        int row = idx >> 7, col = idx & 127;
        *(float4*)&a_lds[row][col] =
            *(const float4*)(hp_t + ((size_t)b * Tq + t0 + row) * Hq + col);
    }
    __syncthreads();

    float4 av = *(const float4*)&a_lds[tq][h8 * 4];
    float4 uv = *(const float4*)(u + h8 * 4);

    const float* cb = c_s + (size_t)b * Tq * Hq + h8 * 4;
    float dsum = 0.f;
#pragma unroll 4
    for (int s = 0; s < 512; ++s) {
        float4 cv = *(const float4*)(cb + (size_t)s * Hq);
        float acc = uv.x * tanh_fast(av.x + cv.x) + uv.y * tanh_fast(av.y + cv.y)
                  + uv.z * tanh_fast(av.z + cv.z) + uv.w * tanh_fast(av.w + cv.w);
        acc += __shfl_xor(acc, 1, 64);
        acc += __shfl_xor(acc, 2, 64);
        acc += __shfl_xor(acc, 4, 64);
        acc += __shfl_xor(acc, 8, 64);
        acc += __shfl_xor(acc, 16, 64);
        float p = __expf(acc);
        if (h8 == 0) sc[tq][s] = p;
        dsum += p;
    }
    float rinv = rcp_fast(dsum);   // all lanes of a tq-group agree
    __syncthreads();

    // PV: R[t][h] = sum_s sc[t][s] * Hsh[s][h]
    const float* hb = Hsh + (size_t)b * Tq * Hq + h8 * 4;
    float ax = 0.f, ay = 0.f, az = 0.f, aw = 0.f;
#pragma unroll 2
    for (int s4 = 0; s4 < 512; s4 += 4) {
        float4 w4 = *(const float4*)&sc[tq][s4];
        float4 v0 = *(const float4*)(hb + (size_t)(s4 + 0) * Hq);
        float4 v1 = *(const float4*)(hb + (size_t)(s4 + 1) * Hq);
        float4 v2 = *(const float4*)(hb + (size_t)(s4 + 2) * Hq);
        float4 v3 = *(const float4*)(hb + (size_t)(s4 + 3) * Hq);
        ax += w4.x * v0.x + w4.y * v1.x + w4.z * v2.x + w4.w * v3.x;
        ay += w4.x * v0.y + w4.y * v1.y + w4.z * v2.y + w4.w * v3.y;
        az += w4.x * v0.z + w4.y * v1.z + w4.z * v2.z + w4.w * v3.z;
        aw += w4.x * v0.w + w4.y * v1.w + w4.z * v2.w + w4.w * v3.w;
    }
    float4 outv = make_float4(ax * rinv, ay * rinv, az * rinv, aw * rinv);
    *(float4*)(R + ((size_t)b * Tq + t0 + tq) * Hq + h8 * 4) = outv;
}

// ---------------------------------------------------------------------------
extern "C" void kernel_launch(void* const* d_in, const int* in_sizes, int n_in,
                              void* d_out, int out_size, void* d_ws, size_t ws_size,
                              hipStream_t stream) {
    const float* x      = (const float*)d_in[0];
    const float* Wih_s  = (const float*)d_in[1];
    const float* Whh_s  = (const float*)d_in[2];
    const float* b_s    = (const float*)d_in[3];
    const float* Wx     = (const float*)d_in[4];
    const float* Wht    = (const float*)d_in[5];
    const float* Whs    = (const float*)d_in[6];
    const float* bs     = (const float*)d_in[7];
    const float* u      = (const float*)d_in[8];
    // d_in[9] = bu: constant shift of scores -> softmax-invariant, unused
    const float* Wih_t  = (const float*)d_in[10];
    const float* Whh_t  = (const float*)d_in[11];
    const float* b_t    = (const float*)d_in[12];
    float* out = (float*)d_out;

    // workspace layout (floats)
    float* ws    = (float*)d_ws;
    float* xg_s  = ws;                 // [B,T,512]
    float* xg_t  = ws + 1048576;       // [B,T,512]
    float* Hsh   = ws + 2097152;       // [B,T,128]
    float* hp_t  = ws + 2359296;       // [B,T,128] (W16_s home until mid writes)
    float* c_s   = ws + 2621440;       // [B,T,128]
    float* Rbuf  = ws + 2883584;       // [B,T,128]
    _Float16* W16_t = (_Float16*)(ws + 3145728);   // tail, survives to lstm2
    _Float16* W16_s = (_Float16*)hp_t;             // consumed by lstm1 before mid

    dim3 blk(256);

    // 1) prep: both input projections + both f16 weight converts
    prep<<<640, blk, 0, stream>>>(x, Wih_s, b_s, Wih_t, b_t, Whh_s, Whh_t,
                                  xg_s, xg_t, W16_s, W16_t);

    // 2) shared LSTM (one block, all 4 batches)
    lstm_b4<<<1, 512, 0, stream>>>(xg_s, W16_s, Hsh);

    // 3) attention precursors: hp_t = Hsh@Wht ; c_s = x@Wx + Hsh@Whs + bs
    mid<<<128, blk, 0, stream>>>(x, Hsh, Wht, Wx, Whs, bs, hp_t, c_s);

    // 4) attention: t-tiled scores + softmax + weighted sum
    attn_kernel<<<dim3(Tq / 8, Bq), blk, 0, stream>>>(hp_t, c_s, u, Hsh, Rbuf);

    // 5) xg_t += R @ Wih_t[:,128:].T
    gemm_nt<<<dim3(32, 8), blk, 0, stream>>>(Rbuf, 128, Wih_t + 128, 256, nullptr, xg_t, 1);

    // 6) task LSTM -> output (one block, all 4 batches)
    lstm_b4<<<1, 512, 0, stream>>>(xg_t, W16_t, out);
}

// Round 13
// 624.939 us; speedup vs baseline: 1.2830x; 1.2830x over previous
//
#include <hip/hip_runtime.h>
#include <hip/hip_bf16.h>
#include <math.h>

// Problem constants: B=4, T=512, I=128, H=128 (4H=512)
#define Bq 4
#define Tq 512
#define Hq 128

typedef _Float16 f16x4 __attribute__((ext_vector_type(4)));
typedef _Float16 f16x8 __attribute__((ext_vector_type(8)));
typedef float f32x4 __attribute__((ext_vector_type(4)));

__device__ __forceinline__ float rcp_fast(float x) { return __builtin_amdgcn_rcpf(x); }
__device__ __forceinline__ float sigmoid_fast(float x) {
    return rcp_fast(1.0f + __expf(-x));
}
__device__ __forceinline__ float tanh_fast(float x) {
    float e = __expf(2.0f * x);
    return 1.0f - 2.0f * rcp_fast(e + 1.0f);
}

// ---------------------------------------------------------------------------
// GEMM-nt body, 256 threads: C[m,n] = sum_k A[m,k]*W[n,k] (+bias)(+=C), K=128.
// ---------------------------------------------------------------------------
__device__ __forceinline__ void gemm_nt_body(float (*As)[68], float (*Ws)[68],
                                             const float* __restrict__ A, int lda,
                                             const float* __restrict__ W, int ldw,
                                             const float* __restrict__ bias,
                                             float* __restrict__ C, int acc_flag,
                                             int m0, int n0, int tid) {
    int tx = tid & 15, ty = tid >> 4;
    float acc[4][4] = {};
    for (int kc = 0; kc < 2; kc++) {
        __syncthreads();
#pragma unroll
        for (int i = 0; i < 4; i++) {
            int idx = tid + 256 * i;
            int r = idx >> 4, c4 = idx & 15;
            *(float4*)(&As[r][c4 * 4]) = *(const float4*)(A + (size_t)(m0 + r) * lda + kc * 64 + c4 * 4);
            *(float4*)(&Ws[r][c4 * 4]) = *(const float4*)(W + (size_t)(n0 + r) * ldw + kc * 64 + c4 * 4);
        }
        __syncthreads();
#pragma unroll
        for (int k4 = 0; k4 < 16; k4++) {
            float4 a[4], wv[4];
#pragma unroll
            for (int i = 0; i < 4; i++) a[i] = *(const float4*)(&As[ty * 4 + i][k4 * 4]);
#pragma unroll
            for (int j = 0; j < 4; j++) wv[j] = *(const float4*)(&Ws[tx * 4 + j][k4 * 4]);
#pragma unroll
            for (int i = 0; i < 4; i++)
#pragma unroll
                for (int j = 0; j < 4; j++)
                    acc[i][j] += a[i].x * wv[j].x + a[i].y * wv[j].y + a[i].z * wv[j].z + a[i].w * wv[j].w;
        }
    }
#pragma unroll
    for (int i = 0; i < 4; i++) {
        int m = m0 + ty * 4 + i;
        int n = n0 + tx * 4;
        float4 v = make_float4(acc[i][0], acc[i][1], acc[i][2], acc[i][3]);
        if (bias) { v.x += bias[n]; v.y += bias[n + 1]; v.z += bias[n + 2]; v.w += bias[n + 3]; }
        if (acc_flag) {
            float4 o = *(const float4*)(C + (size_t)m * 512 + n);
            v.x += o.x; v.y += o.y; v.z += o.z; v.w += o.w;
        }
        *(float4*)(C + (size_t)m * 512 + n) = v;
    }
}

// ---------------------------------------------------------------------------
// GEMM-nt body, 512 threads (for lstm-shadow side blocks). Tile 64x64, K=128.
// Thread (tx=tid&15 -> 4 cols, ty=tid>>4 in 0..32 -> 2 rows).
// ---------------------------------------------------------------------------
__device__ __forceinline__ void gemm_nt_512(float (*As)[68], float (*Ws)[68],
                                            const float* __restrict__ A, int lda,
                                            const float* __restrict__ W, int ldw,
                                            const float* __restrict__ bias,
                                            float* __restrict__ C,
                                            int m0, int n0, int tid) {
    int tx = tid & 15, ty = tid >> 4;   // ty 0..31
    float acc[2][4] = {};
    for (int kc = 0; kc < 2; kc++) {
        __syncthreads();
#pragma unroll
        for (int i = 0; i < 2; i++) {
            int idx = tid + 512 * i;            // 0..1023
            int r = idx >> 4, c4 = idx & 15;
            *(float4*)(&As[r][c4 * 4]) = *(const float4*)(A + (size_t)(m0 + r) * lda + kc * 64 + c4 * 4);
            *(float4*)(&Ws[r][c4 * 4]) = *(const float4*)(W + (size_t)(n0 + r) * ldw + kc * 64 + c4 * 4);
        }
        __syncthreads();
#pragma unroll
        for (int k4 = 0; k4 < 16; k4++) {
            float4 a[2], wv[4];
#pragma unroll
            for (int i = 0; i < 2; i++) a[i] = *(const float4*)(&As[ty * 2 + i][k4 * 4]);
#pragma unroll
            for (int j = 0; j < 4; j++) wv[j] = *(const float4*)(&Ws[tx * 4 + j][k4 * 4]);
#pragma unroll
            for (int i = 0; i < 2; i++)
#pragma unroll
                for (int j = 0; j < 4; j++)
                    acc[i][j] += a[i].x * wv[j].x + a[i].y * wv[j].y + a[i].z * wv[j].z + a[i].w * wv[j].w;
        }
    }
#pragma unroll
    for (int i = 0; i < 2; i++) {
        int m = m0 + ty * 2 + i;
        int n = n0 + tx * 4;
        float4 v = make_float4(acc[i][0], acc[i][1], acc[i][2], acc[i][3]);
        if (bias) { v.x += bias[n]; v.y += bias[n + 1]; v.z += bias[n + 2]; v.w += bias[n + 3]; }
        *(float4*)(C + (size_t)m * 512 + n) = v;
    }
}

// ---------------------------------------------------------------------------
// prep: xg_s projection (256 tiles) + W16_s convert (64 blocks). grid 320.
// ---------------------------------------------------------------------------
__global__ __launch_bounds__(256) void prep(const float* __restrict__ x,
                                            const float* __restrict__ Wih_s,
                                            const float* __restrict__ b_s,
                                            const float* __restrict__ Whh_s,
                                            float* __restrict__ xg_s,
                                            _Float16* __restrict__ W16_s) {
    __shared__ __align__(16) float As[64][68];
    __shared__ __align__(16) float Ws[64][68];
    int bid = blockIdx.x;
    int tid = threadIdx.x;
    if (bid < 256) {
        gemm_nt_body(As, Ws, x, 128, Wih_s, 128, b_s, xg_s, 0,
                     (bid & 31) * 64, (bid >> 5) * 64, tid);
    } else {
        int cb = bid - 256;                      // 0..63
        int i = (cb * 256 + tid) * 4;
        float4 v = *(const float4*)(Whh_s + i);
        f16x4 o;
        o[0] = (_Float16)v.x; o[1] = (_Float16)v.y;
        o[2] = (_Float16)v.z; o[3] = (_Float16)v.w;
        *(f16x4*)(W16_s + i) = o;
    }
}

// ---------------------------------------------------------------------------
// gemm_nt standalone (R-projection accumulate). grid (32,8), block 256.
// ---------------------------------------------------------------------------
__global__ __launch_bounds__(256) void gemm_nt(const float* __restrict__ A, int lda,
                                               const float* __restrict__ W, int ldw,
                                               const float* __restrict__ bias,
                                               float* __restrict__ C, int acc_flag) {
    __shared__ __align__(16) float As[64][68];
    __shared__ __align__(16) float Ws[64][68];
    gemm_nt_body(As, Ws, A, lda, W, ldw, bias, C, acc_flag,
                 blockIdx.x * 64, blockIdx.y * 64, threadIdx.x);
}

// ---------------------------------------------------------------------------
// mid: both attention-precursor GEMMs in one launch. flat grid 128.
// ---------------------------------------------------------------------------
__global__ __launch_bounds__(256) void mid(const float* __restrict__ x,
                                           const float* __restrict__ Hsh,
                                           const float* __restrict__ Wht,
                                           const float* __restrict__ Wx,
                                           const float* __restrict__ Whs,
                                           const float* __restrict__ bs,
                                           float* __restrict__ hp_t,
                                           float* __restrict__ c_s) {
    __shared__ __align__(16) float As[64][68];
    __shared__ __align__(16) float Bs[64][68];
    int bid = blockIdx.x;
    int cfg = bid >> 6;          // 0: hp_t, 1: c_s
    int b2 = bid & 63;
    int m0 = (b2 & 31) * 64, n0 = (b2 >> 5) * 64;
    const float* A1 = cfg ? x : Hsh;
    const float* B1 = cfg ? Wx : Wht;
    const float* A2 = cfg ? Hsh : nullptr;
    const float* B2 = cfg ? Whs : nullptr;
    const float* bias = cfg ? bs : nullptr;
    float* C = cfg ? c_s : hp_t;

    int tid = threadIdx.x;
    int tx = tid & 15, ty = tid >> 4;
    float acc[4][4] = {};
    for (int src = 0; src < 2; src++) {
        const float* A = src ? A2 : A1;
        const float* Bm = src ? B2 : B1;
        if (!A) break;
        for (int kc = 0; kc < 2; kc++) {
            __syncthreads();
#pragma unroll
            for (int i = 0; i < 4; i++) {
                int idx = tid + 256 * i;
                int r = idx >> 4, c4 = idx & 15;
                *(float4*)(&As[r][c4 * 4]) = *(const float4*)(A + (size_t)(m0 + r) * 128 + kc * 64 + c4 * 4);
                *(float4*)(&Bs[r][c4 * 4]) = *(const float4*)(Bm + (size_t)(kc * 64 + r) * 128 + n0 + c4 * 4);
            }
            __syncthreads();
#pragma unroll
            for (int k4 = 0; k4 < 16; k4++) {
                float4 a[4];
#pragma unroll
                for (int i = 0; i < 4; i++) a[i] = *(const float4*)(&As[ty * 4 + i][k4 * 4]);
#pragma unroll
                for (int kk = 0; kk < 4; kk++) {
                    float4 bv = *(const float4*)(&Bs[k4 * 4 + kk][tx * 4]);
#pragma unroll
                    for (int i = 0; i < 4; i++) {
                        float av = (kk == 0) ? a[i].x : (kk == 1) ? a[i].y : (kk == 2) ? a[i].z : a[i].w;
                        acc[i][0] += av * bv.x;
                        acc[i][1] += av * bv.y;
                        acc[i][2] += av * bv.z;
                        acc[i][3] += av * bv.w;
                    }
                }
            }
        }
    }
#pragma unroll
    for (int i = 0; i < 4; i++) {
        int m = m0 + ty * 4 + i;
        int n = n0 + tx * 4;
        float4 v = make_float4(acc[i][0], acc[i][1], acc[i][2], acc[i][3]);
        if (bias) { v.x += bias[n]; v.y += bias[n + 1]; v.z += bias[n + 2]; v.w += bias[n + 3]; }
        *(float4*)(C + (size_t)m * 128 + n) = v;
    }
}

// ---------------------------------------------------------------------------
// LSTM core (R11-proven): all 4 batches, 512 threads, AGPR-pinned weights,
// zero-acc trick, depth-2 MFMA chains, running pointers, lean barrier.
// ---------------------------------------------------------------------------
#define MF0(ACC, A, B) \
    asm("v_mfma_f32_16x16x32_f16 %0, %1, %2, %3" : "=&v"(ACC) : "v"(A), "a"(B), "v"(zro));
#define MF(ACC, A, B) \
    asm("v_mfma_f32_16x16x32_f16 %0, %1, %2, %0" : "+v"(ACC) : "v"(A), "a"(B));

#define LSTM_STEP(X0, X1, X2, X3, R0, R1, R2, R3, WPTR, PXG)                       \
    {                                                                              \
        f16x8 a0 = *(R0); f16x8 a1 = *(R1);                                        \
        f16x8 a2 = *(R2); f16x8 a3 = *(R3);                                        \
        float o0 = X0, o1 = X1, o2 = X2, o3 = X3;                                  \
        X0 = (PXG)[0]; X1 = (PXG)[128]; X2 = (PXG)[256]; X3 = (PXG)[384];          \
        (PXG) += 1024;                                                             \
        f32x4 ac0a, ac1a, ac2a, ac3a, ac0b, ac1b, ac2b, ac3b;                      \
        MF0(ac0a, a0, b00) MF0(ac1a, a0, b10) MF0(ac2a, a0, b20) MF0(ac3a, a0, b30)\
        MF0(ac0b, a2, b02) MF0(ac1b, a2, b12) MF0(ac2b, a2, b22) MF0(ac3b, a2, b32)\
        MF(ac0a, a1, b01) MF(ac1a, a1, b11) MF(ac2a, a1, b21) MF(ac3a, a1, b31)    \
        MF(ac0b, a3, b03) MF(ac1b, a3, b13) MF(ac2b, a3, b23) MF(ac3b, a3, b33)    \
        asm volatile("s_nop 7\n\ts_nop 7"                                          \
                     : "+v"(ac0a), "+v"(ac1a), "+v"(ac2a), "+v"(ac3a),             \
                       "+v"(ac0b), "+v"(ac1b), "+v"(ac2b), "+v"(ac3b));            \
        float gi = ac0a[0] + ac0b[0] + o0;                                         \
        float gf = ac1a[0] + ac1b[0] + o1;                                         \
        float gg = ac2a[0] + ac2b[0] + o2;                                         \
        float go = ac3a[0] + ac3b[0] + o3;                                         \
        float si = sigmoid_fast(gi), sf = sigmoid_fast(gf), so = sigmoid_fast(go); \
        float tg = tanh_fast(gg);                                                  \
        c = sf * c + si * tg;                                                      \
        float h = so * tanh_fast(c);                                               \
        *(WPTR) = (_Float16)h;                                                     \
        *pH = h; pH += Hq;                                                         \
        __builtin_amdgcn_sched_barrier(0);                                         \
        asm volatile("s_waitcnt lgkmcnt(0)");                                      \
        __builtin_amdgcn_s_barrier();                                              \
        __builtin_amdgcn_sched_barrier(0);                                         \
    }

__device__ __forceinline__ void lstm_core(const float* __restrict__ xg,
                                          const _Float16* __restrict__ W16,
                                          float* __restrict__ Hout,
                                          _Float16* hbase, int tid) {
    int w = tid >> 6, lane = tid & 63;
    int r = lane & 15, kg = lane >> 4;   // kg = k-group AND batch id
    int ch = 16 * w + r;

    for (int i = tid; i < 4096; i += 512) hbase[i] = (_Float16)0.f;

    const _Float16* wb = W16 + (size_t)ch * 128 + kg * 8;
#define LWB(g, kb) *(const f16x8*)(wb + (size_t)(g) * 16384 + (kb) * 32)
    f16x8 b00 = LWB(0, 0), b01 = LWB(0, 1), b02 = LWB(0, 2), b03 = LWB(0, 3);
    f16x8 b10 = LWB(1, 0), b11 = LWB(1, 1), b12 = LWB(1, 2), b13 = LWB(1, 3);
    f16x8 b20 = LWB(2, 0), b21 = LWB(2, 1), b22 = LWB(2, 2), b23 = LWB(2, 3);
    f16x8 b30 = LWB(3, 0), b31 = LWB(3, 1), b32 = LWB(3, 2), b33 = LWB(3, 3);
#undef LWB
    f32x4 zro = {0.f, 0.f, 0.f, 0.f};
    asm volatile(""
                 : "+a"(b00), "+a"(b01), "+a"(b02), "+a"(b03),
                   "+a"(b10), "+a"(b11), "+a"(b12), "+a"(b13),
                   "+a"(b20), "+a"(b21), "+a"(b22), "+a"(b23),
                   "+a"(b30), "+a"(b31), "+a"(b32), "+a"(b33),
                   "+v"(zro));

    int aoff0 = r * 128 + (((0 * 4 + kg) ^ r) << 3);
    int aoff1 = r * 128 + (((1 * 4 + kg) ^ r) << 3);
    int aoff2 = r * 128 + (((2 * 4 + kg) ^ r) << 3);
    int aoff3 = r * 128 + (((3 * 4 + kg) ^ r) << 3);
    int woff = (4 * kg) * 128 + (((ch >> 3) ^ (4 * kg)) << 3) + (ch & 7);

    const f16x8* rA0 = (const f16x8*)(hbase + aoff0);
    const f16x8* rA1 = (const f16x8*)(hbase + aoff1);
    const f16x8* rA2 = (const f16x8*)(hbase + aoff2);
    const f16x8* rA3 = (const f16x8*)(hbase + aoff3);
    const f16x8* rB0 = (const f16x8*)(hbase + 2048 + aoff0);
    const f16x8* rB1 = (const f16x8*)(hbase + 2048 + aoff1);
    const f16x8* rB2 = (const f16x8*)(hbase + 2048 + aoff2);
    const f16x8* rB3 = (const f16x8*)(hbase + 2048 + aoff3);
    _Float16* wA = hbase + 2048 + woff;
    _Float16* wB = hbase + woff;

    size_t kgTq = (size_t)kg * Tq;
    const float* p0 = xg + (kgTq + 0) * 512 + ch;
    const float* p1 = xg + (kgTq + 1) * 512 + ch;
    float xa0 = p0[0], xa1 = p0[128], xa2 = p0[256], xa3 = p0[384];
    float xb0 = p1[0], xb1 = p1[128], xb2 = p1[256], xb3 = p1[384];
    const float* pA = xg + (kgTq + 2) * 512 + ch;
    const float* pB = xg + (kgTq + 3) * 512 + ch;
    float* pH = Hout + kgTq * Hq + ch;

    float c = 0.f;
    __syncthreads();

    for (int t = 0; t < Tq; t += 2) {
        LSTM_STEP(xa0, xa1, xa2, xa3, rA0, rA1, rA2, rA3, wA, pA)
        LSTM_STEP(xb0, xb1, xb2, xb3, rB0, rB1, rB2, rB3, wB, pB)
    }
}

// ---------------------------------------------------------------------------
// lstm_fused: block 0 = shared-LSTM recurrence (1 CU); blocks 1..256 run the
// xg_t input projection; blocks 257..320 convert Whh_t->f16 -- all under the
// recurrence's 238us shadow on otherwise-idle CUs (no inter-block deps).
// ---------------------------------------------------------------------------
__global__ __launch_bounds__(512)
__attribute__((amdgpu_waves_per_eu(2, 2)))
void lstm_fused(const float* __restrict__ xg_s,
                const _Float16* __restrict__ W16_s,
                float* __restrict__ Hsh,
                const float* __restrict__ x,
                const float* __restrict__ Wih_t,
                const float* __restrict__ b_t,
                const float* __restrict__ Whh_t,
                float* __restrict__ xg_t,
                _Float16* __restrict__ W16_t) {
    __shared__ __align__(16) float smem[2][64][68];
    int bid = blockIdx.x;
    int tid = threadIdx.x;
    if (bid == 0) {
        lstm_core(xg_s, W16_s, Hsh, (_Float16*)&smem[0][0][0], tid);
    } else if (bid <= 256) {
        int b2 = bid - 1;
        gemm_nt_512(smem[0], smem[1], x, 128, Wih_t, 256, b_t, xg_t,
                    (b2 & 31) * 64, (b2 >> 5) * 64, tid);
    } else {
        int cb = bid - 257;                      // 0..63
        int i = (cb * 512 + tid) * 2;
        float2 v = *(const float2*)(Whh_t + i);
        W16_t[i] = (_Float16)v.x;
        W16_t[i + 1] = (_Float16)v.y;
    }
}

// ---------------------------------------------------------------------------
// lstm_b4 plain (task LSTM). grid 1, block 512.
// ---------------------------------------------------------------------------
__global__ __launch_bounds__(512)
__attribute__((amdgpu_waves_per_eu(2, 2)))
void lstm_b4(const float* __restrict__ xg,
             const _Float16* __restrict__ W16,
             float* __restrict__ Hout) {
    __shared__ _Float16 hbuf[2][16][128];
    lstm_core(xg, W16, Hout, &hbuf[0][0][0], threadIdx.x);
}

// ---------------------------------------------------------------------------
// Attention (R11-proven): coalesced scores, lane=(h4,s2), 4-stage shfl
// h-reduce, no max-subtraction, full-occupancy grid (T,B) x 256.
// ---------------------------------------------------------------------------
__global__ __launch_bounds__(256) void attn_kernel(const float* __restrict__ hp_t,
                                                   const float* __restrict__ c_s,
                                                   const float* __restrict__ u,
                                                   const float* __restrict__ Hsh,
                                                   float* __restrict__ R) {
    int t = blockIdx.x, b = blockIdx.y;
    int tid = threadIdx.x;
    __shared__ __align__(16) float a_lds[128];
    __shared__ __align__(16) float u_lds[128];
    __shared__ __align__(16) float sc[512];
    __shared__ __align__(16) float red[256];

    if (tid < 128) {
        a_lds[tid] = hp_t[((size_t)b * Tq + t) * Hq + tid];
        u_lds[tid] = u[tid];
    }
    __syncthreads();

    int lane = tid & 63, wv = tid >> 6;
    int h4 = lane & 15, s2 = lane >> 4;
    float4 a0 = *(const float4*)(&a_lds[h4 * 4]);
    float4 a1 = *(const float4*)(&a_lds[64 + h4 * 4]);
    float4 u0 = *(const float4*)(&u_lds[h4 * 4]);
    float4 u1 = *(const float4*)(&u_lds[64 + h4 * 4]);

    const float* cb = c_s + (size_t)b * Tq * Hq;
    float psum = 0.0f;
#pragma unroll 4
    for (int it = 0; it < 32; ++it) {
        int s = it * 16 + wv * 4 + s2;
        const float4* crow = (const float4*)(cb + (size_t)s * Hq);
        float4 c0 = crow[h4];
        float4 c1 = crow[h4 + 16];
        float acc = u0.x * tanh_fast(a0.x + c0.x) + u0.y * tanh_fast(a0.y + c0.y)
                  + u0.z * tanh_fast(a0.z + c0.z) + u0.w * tanh_fast(a0.w + c0.w)
                  + u1.x * tanh_fast(a1.x + c1.x) + u1.y * tanh_fast(a1.y + c1.y)
                  + u1.z * tanh_fast(a1.z + c1.z) + u1.w * tanh_fast(a1.w + c1.w);
        acc += __shfl_xor(acc, 1, 64);
        acc += __shfl_xor(acc, 2, 64);
        acc += __shfl_xor(acc, 4, 64);
        acc += __shfl_xor(acc, 8, 64);
        if (h4 == 0) {
            float p = __expf(acc);
            sc[s] = p;
            psum += p;
        }
    }
#pragma unroll
    for (int off = 1; off < 64; off <<= 1) psum += __shfl_xor(psum, off, 64);
    if (lane == 0) red[wv] = psum;
    __syncthreads();
    float rinv = rcp_fast(red[0] + red[1] + red[2] + red[3]);

    int h = tid & 127, half = tid >> 7;
    float acc = 0.0f;
    for (int s = half; s < 512; s += 2) {
        acc += sc[s] * Hsh[((size_t)b * Tq + s) * Hq + h];
    }
    red[tid] = acc;
    __syncthreads();
    if (tid < 128) {
        R[((size_t)b * Tq + t) * Hq + tid] = (red[tid] + red[tid + 128]) * rinv;
    }
}

// ---------------------------------------------------------------------------
extern "C" void kernel_launch(void* const* d_in, const int* in_sizes, int n_in,
                              void* d_out, int out_size, void* d_ws, size_t ws_size,
                              hipStream_t stream) {
    const float* x      = (const float*)d_in[0];
    const float* Wih_s  = (const float*)d_in[1];
    const float* Whh_s  = (const float*)d_in[2];
    const float* b_s    = (const float*)d_in[3];
    const float* Wx     = (const float*)d_in[4];
    const float* Wht    = (const float*)d_in[5];
    const float* Whs    = (const float*)d_in[6];
    const float* bs     = (const float*)d_in[7];
    const float* u      = (const float*)d_in[8];
    // d_in[9] = bu: softmax-invariant, unused
    const float* Wih_t  = (const float*)d_in[10];
    const float* Whh_t  = (const float*)d_in[11];
    const float* b_t    = (const float*)d_in[12];
    float* out = (float*)d_out;

    // workspace layout (floats)
    float* ws    = (float*)d_ws;
    float* xg_s  = ws;                 // [B,T,512]
    float* xg_t  = ws + 1048576;       // [B,T,512]
    float* Hsh   = ws + 2097152;       // [B,T,128]
    float* hp_t  = ws + 2359296;       // [B,T,128] (W16_s home until mid writes)
    float* c_s   = ws + 2621440;       // [B,T,128]
    float* Rbuf  = ws + 2883584;       // [B,T,128]
    _Float16* W16_t = (_Float16*)(ws + 3145728);   // tail, survives to lstm2
    _Float16* W16_s = (_Float16*)hp_t;             // consumed by lstm1 before mid

    dim3 blk(256);

    // 1) prep: xg_s projection + W16_s convert (critical path to lstm1)
    prep<<<320, blk, 0, stream>>>(x, Wih_s, b_s, Whh_s, xg_s, W16_s);

    // 2) shared LSTM (block 0) + xg_t projection + W16_t convert (shadow)
    lstm_fused<<<321, 512, 0, stream>>>(xg_s, W16_s, Hsh,
                                        x, Wih_t, b_t, Whh_t, xg_t, W16_t);

    // 3) attention precursors: hp_t = Hsh@Wht ; c_s = x@Wx + Hsh@Whs + bs
    mid<<<128, blk, 0, stream>>>(x, Hsh, Wht, Wx, Whs, bs, hp_t, c_s);

    // 4) attention scores + softmax + weighted sum (R11 kernel)
    attn_kernel<<<dim3(Tq, Bq), blk, 0, stream>>>(hp_t, c_s, u, Hsh, Rbuf);

    // 5) xg_t += R @ Wih_t[:,128:].T
    gemm_nt<<<dim3(32, 8), blk, 0, stream>>>(Rbuf, 128, Wih_t + 128, 256, nullptr, xg_t, 1);

    // 6) task LSTM -> output
    lstm_b4<<<1, 512, 0, stream>>>(xg_t, W16_t, out);
}